// Round 5
// baseline (279.974 us; speedup 1.0000x reference)
//
#include <hip/hip_runtime.h>
#include <cstdint>
#include <cstddef>

#define DEVI __device__ __forceinline__

typedef short bf16x8 __attribute__((ext_vector_type(8)));
typedef short bf16x4 __attribute__((ext_vector_type(4)));
typedef float f32x4 __attribute__((ext_vector_type(4)));
typedef float f32x16 __attribute__((ext_vector_type(16)));
typedef unsigned short u16x4 __attribute__((ext_vector_type(4)));

constexpr int D_MODEL = 1024;
constexpr int HEADS = 16;
constexpr int DH = 64;
constexpr int SEQ = 2048;
constexpr int KDIM = 1024;

DEVI unsigned short f2bf(float f) {
  union { float f; unsigned u; } v; v.f = f;
  unsigned r = v.u + 0x7fffu + ((v.u >> 16) & 1u);
  return (unsigned short)(r >> 16);
}

// pack two fp32 -> two TRUNCATED bf16 in one dword (a = low16, b = high16)
DEVI unsigned pkbf(float a, float b) {
  return __builtin_amdgcn_perm(__float_as_uint(b), __float_as_uint(a), 0x07060302u);
}

// pack two fp32 -> two RTNE-rounded bf16 in one dword
DEVI unsigned pkbf_rn(float a, float b) {
  unsigned ua = __float_as_uint(a); ua += 0x7fffu + ((ua >> 16) & 1u);
  unsigned ub = __float_as_uint(b); ub += 0x7fffu + ((ub >> 16) & 1u);
  return __builtin_amdgcn_perm(ub, ua, 0x07060302u);
}

DEVI void cp16(const void* g, void* l) {
  __builtin_amdgcn_global_load_lds(
      (const __attribute__((address_space(1))) void*)g,
      (__attribute__((address_space(3))) void*)l, 16, 0, 0);
}

DEVI f32x16 mfma_32x32x8(bf16x4 a, bf16x4 b, f32x16 c) {
#if __has_builtin(__builtin_amdgcn_mfma_f32_32x32x8bf16_1k)
  return __builtin_amdgcn_mfma_f32_32x32x8bf16_1k(a, b, c, 0, 0, 0);
#else
  asm volatile("v_mfma_f32_32x32x8_bf16 %0, %1, %2, %0" : "+v"(c) : "v"(a), "v"(b));
  return c;
#endif
}

// ---------------- fp32 -> bf16 cast, weights only ----------------
__global__ void __launch_bounds__(256) castW(
    const float* __restrict__ Wq, const float* __restrict__ Wk,
    const float* __restrict__ Wv, const float* __restrict__ Wo,
    unsigned short* __restrict__ Wqb, unsigned short* __restrict__ Wkb,
    unsigned short* __restrict__ Wvb, unsigned short* __restrict__ Wob) {
  int bid = blockIdx.x;
  int w = bid >> 10, off = bid & 1023;
  const float* s = (w == 0) ? Wq : ((w == 1) ? Wk : ((w == 2) ? Wv : Wo));
  unsigned short* d = (w == 0) ? Wqb : ((w == 1) ? Wkb : ((w == 2) ? Wvb : Wob));
  int i = (off * 256 + threadIdx.x) * 4;
  float4 x = *(const float4*)(s + i);
  u16x4 o; o[0] = f2bf(x.x); o[1] = f2bf(x.y); o[2] = f2bf(x.z); o[3] = f2bf(x.w);
  *(u16x4*)(d + i) = o;
}

// ---------------- fused QKV projection: 128x128 tile, fp32 A staged, inline pack ----
// C = A[M,K](fp32) * W[N,K]^T(bf16) + bias. mode 0 -> [B,H,S,Dh]; mode 1 -> [B,H,Dh,S].
__global__ void __launch_bounds__(256) qkv_gemm(
    const float* __restrict__ qf, const float* __restrict__ kf, const float* __restrict__ vf,
    const unsigned short* __restrict__ Wqb, const unsigned short* __restrict__ Wkb,
    const unsigned short* __restrict__ Wvb,
    const float* __restrict__ bq, const float* __restrict__ bk, const float* __restrict__ bv,
    unsigned short* __restrict__ Qh, unsigned short* __restrict__ Kh,
    unsigned short* __restrict__ Vt, float qscale) {
  __shared__ float Asf[128 * 32];          // fp32 A tile, 16 KB
  __shared__ unsigned short Bs[128 * 32];  // bf16 W tile, 8 KB
  const int bid = blockIdx.x, seg = bid >> 8, inner = bid & 255;
  const int bm = inner >> 3, bn = inner & 7;
  const float* A = (seg == 0) ? qf : ((seg == 1) ? kf : vf);
  const unsigned short* W = (seg == 0) ? Wqb : ((seg == 1) ? Wkb : Wvb);
  const float* bias = (seg == 0) ? bq : ((seg == 1) ? bk : bv);
  unsigned short* O = (seg == 0) ? Qh : ((seg == 1) ? Kh : Vt);
  const float oscale = (seg == 0) ? qscale : 1.0f;
  const int mode = (seg == 2) ? 1 : 0;

  const int tid = threadIdx.x, lane = tid & 63, wave = tid >> 6;
  const int l16 = lane & 15, quad = lane >> 4;
  const int wm = (wave >> 1) * 64, wn = (wave & 1) * 64;
  const int sw = (l16 >> 1) & 3;
  f32x4 acc[4][4] = {};

  for (int k0 = 0; k0 < KDIM; k0 += 32) {
    // A: 128 rows x 32 fp32 = 1024 16B-chunks; swizzle: phys blk p of row r = p^(r&7)
#pragma unroll
    for (int c = 0; c < 4; ++c) {
      int slot = c * 256 + tid;
      int row = slot >> 3, pb = slot & 7;
      int jb = pb ^ (row & 7);
      cp16(A + (size_t)(bm * 128 + row) * KDIM + k0 + jb * 4, &Asf[slot * 4]);
    }
    // W: 128 rows x 32 bf16 = 512 chunks; swizzle ^((row>>1)&3)
#pragma unroll
    for (int c = 0; c < 2; ++c) {
      int slot = c * 256 + tid;
      int row = slot >> 2, pb = slot & 3;
      int col = (pb ^ ((row >> 1) & 3)) * 8;
      cp16(W + (size_t)(bn * 128 + row) * KDIM + k0 + col, &Bs[slot * 8]);
    }
    asm volatile("s_waitcnt vmcnt(0)" ::: "memory");
    __syncthreads();

    bf16x8 af[4], bfr[4];
#pragma unroll
    for (int t = 0; t < 4; ++t) {
      const int row = wm + t * 16 + l16;
      const int s8 = row & 7;
      f32x4 lo = *(const f32x4*)&Asf[row * 32 + ((2 * quad) ^ s8) * 4];
      f32x4 hi = *(const f32x4*)&Asf[row * 32 + ((2 * quad + 1) ^ s8) * 4];
      union { unsigned u[4]; bf16x8 v; } cvt;
      cvt.u[0] = pkbf_rn(lo[0], lo[1]);
      cvt.u[1] = pkbf_rn(lo[2], lo[3]);
      cvt.u[2] = pkbf_rn(hi[0], hi[1]);
      cvt.u[3] = pkbf_rn(hi[2], hi[3]);
      af[t] = cvt.v;
    }
#pragma unroll
    for (int t = 0; t < 4; ++t)
      bfr[t] = *(const bf16x8*)&Bs[(wn + t * 16 + l16) * 32 + ((quad ^ sw) * 8)];
#pragma unroll
    for (int i = 0; i < 4; ++i)
#pragma unroll
      for (int j = 0; j < 4; ++j)
        acc[i][j] = __builtin_amdgcn_mfma_f32_16x16x32_bf16(af[i], bfr[j], acc[i][j], 0, 0, 0);
    __syncthreads();
  }

#pragma unroll
  for (int i = 0; i < 4; ++i) {
#pragma unroll
    for (int j = 0; j < 4; ++j) {
      const int col = bn * 128 + wn + j * 16 + l16;
      const float bv = bias[col];
#pragma unroll
      for (int r = 0; r < 4; ++r) {
        const int row = bm * 128 + wm + i * 16 + quad * 4 + r;
        const float val = (acc[i][j][r] + bv) * oscale;
        const int b = row >> 11, s = row & (SEQ - 1);
        const int h = col >> 6, d = col & (DH - 1);
        size_t idx;
        if (mode == 0) idx = ((size_t)(b * HEADS + h) * SEQ + s) * DH + d;
        else           idx = ((size_t)(b * HEADS + h) * DH + d) * SEQ + s;
        O[idx] = f2bf(val);
      }
    }
  }
}

// ---------------- output projection: 64x128 tile, bf16 A ----------------
__global__ void __launch_bounds__(256) out_gemm(const unsigned short* __restrict__ AO,
                                                const unsigned short* __restrict__ Wob,
                                                const float* __restrict__ bo,
                                                float* __restrict__ out) {
  __shared__ unsigned short As[64 * 32], Bs[128 * 32];
  const int bid = blockIdx.x, bm = bid >> 3, bn = bid & 7;
  const int tid = threadIdx.x, lane = tid & 63, wave = tid >> 6;
  const int l16 = lane & 15, quad = lane >> 4;
  const int wn = wave * 32;
  const int sw = (l16 >> 1) & 3;
  f32x4 acc[4][2] = {};

  for (int k0 = 0; k0 < KDIM; k0 += 32) {
    {
      int row = tid >> 2, pblk = tid & 3;
      int col = (pblk ^ ((row >> 1) & 3)) * 8;
      cp16(AO + (size_t)(bm * 64 + row) * KDIM + k0 + col, &As[tid * 8]);
    }
#pragma unroll
    for (int c = 0; c < 2; ++c) {
      int slot = c * 256 + tid;
      int row = slot >> 2, pblk = slot & 3;
      int col = (pblk ^ ((row >> 1) & 3)) * 8;
      cp16(Wob + (size_t)(bn * 128 + row) * KDIM + k0 + col, &Bs[slot * 8]);
    }
    asm volatile("s_waitcnt vmcnt(0)" ::: "memory");
    __syncthreads();
    bf16x8 af[4], bfr[2];
#pragma unroll
    for (int t = 0; t < 4; ++t)
      af[t] = *(const bf16x8*)&As[(t * 16 + l16) * 32 + ((quad ^ sw) * 8)];
#pragma unroll
    for (int u = 0; u < 2; ++u)
      bfr[u] = *(const bf16x8*)&Bs[(wn + u * 16 + l16) * 32 + ((quad ^ sw) * 8)];
#pragma unroll
    for (int i = 0; i < 4; ++i)
#pragma unroll
      for (int j = 0; j < 2; ++j)
        acc[i][j] = __builtin_amdgcn_mfma_f32_16x16x32_bf16(af[i], bfr[j], acc[i][j], 0, 0, 0);
    __syncthreads();
  }

#pragma unroll
  for (int i = 0; i < 4; ++i)
#pragma unroll
    for (int j = 0; j < 2; ++j) {
      const int col = bn * 128 + wn + j * 16 + l16;
      const float bv = bo[col];
#pragma unroll
      for (int r = 0; r < 4; ++r) {
        const int row = bm * 64 + i * 16 + quad * 4 + r;
        out[(size_t)row * D_MODEL + col] = acc[i][j][r] + bv;
      }
    }
}

// ---------------- flash attention, 32x32 register-resident P ----------------
// (unchanged from R4 — left out of this round's experiment)
__global__ void __launch_bounds__(256) attn(const unsigned short* __restrict__ Qh,
                                            const unsigned short* __restrict__ Kh,
                                            const unsigned short* __restrict__ Vt,
                                            unsigned short* __restrict__ AO) {
  __shared__ __align__(16) char smem[32768];
  unsigned short* Ks = (unsigned short*)smem;            // [128 key][64 dh]
  unsigned short* Vs = (unsigned short*)(smem + 16384);  // [64 d][128 key]

  const int bid = blockIdx.x;
  const int qt = bid >> 5, head = bid & 31, b = head >> 4, h = head & 15;
  const int tid = threadIdx.x;
  const int lane = tid & 63, wave = tid >> 6;
  const int wq = wave >> 1, wk = wave & 1;
  const int l31 = lane & 31, hh = lane >> 5;

  const unsigned short* Qhead = Qh + (size_t)(b * HEADS + h) * SEQ * DH;
  const unsigned short* Khead = Kh + (size_t)(b * HEADS + h) * SEQ * DH;
  const unsigned short* Vhead = Vt + (size_t)(b * HEADS + h) * DH * SEQ;

  const int qrow = qt * 64 + wq * 32 + l31;
  bf16x8 aq[4];
#pragma unroll
  for (int it = 0; it < 4; ++it)
    aq[it] = *(const bf16x8*)&Qhead[(size_t)qrow * DH + it * 16 + hh * 8];

  f32x16 oacc[2] = {};
  float lsum = 0.f;

  for (int kc = 0; kc < SEQ / 128; ++kc) {
#pragma unroll
    for (int c = 0; c < 4; ++c) {
      int s = c * 256 + tid;
      int row = s >> 3, pblk = s & 7;
      int jb = pblk ^ (row & 7);
      cp16(Khead + (size_t)(kc * 128 + row) * DH + jb * 8, &Ks[s * 8]);
    }
#pragma unroll
    for (int c = 0; c < 4; ++c) {
      int s = c * 256 + tid;
      int d = s >> 4, pblk = s & 15;
      int jb = pblk ^ (d & 7);
      cp16(Vhead + (size_t)d * SEQ + kc * 128 + jb * 8, &Vs[s * 8]);
    }
    asm volatile("s_waitcnt vmcnt(0)" ::: "memory");
    __syncthreads();

#pragma unroll
    for (int sub = 0; sub < 2; ++sub) {
      const int kb32 = sub * 64 + wk * 32;
      const int key = kb32 + l31;

      f32x16 sa = {};
#pragma unroll
      for (int it = 0; it < 4; ++it) {
        const int sblk = (2 * it + hh) ^ (key & 7);
        bf16x8 ak = *(const bf16x8*)&Ks[key * 64 + sblk * 8];
        sa = __builtin_amdgcn_mfma_f32_32x32x16_bf16(ak, aq[it], sa, 0, 0, 0);
      }

      float p[16];
#pragma unroll
      for (int r = 0; r < 16; ++r) {
        p[r] = __builtin_amdgcn_exp2f(sa[r]);
        lsum += p[r];
      }
      bf16x4 pk[4];
#pragma unroll
      for (int g = 0; g < 4; ++g) {
        union { unsigned u[2]; bf16x4 s; } c;
        c.u[0] = pkbf(p[4 * g + 0], p[4 * g + 1]);
        c.u[1] = pkbf(p[4 * g + 2], p[4 * g + 3]);
        pk[g] = c.s;
      }

#pragma unroll
      for (int g = 0; g < 4; ++g) {
        const int gblk = sub * 8 + wk * 4 + g;
#pragma unroll
        for (int dh2 = 0; dh2 < 2; ++dh2) {
          const int d = dh2 * 32 + l31;
          const int sv = gblk ^ (d & 7);
          bf16x4 av = *(const bf16x4*)&Vs[d * 128 + sv * 8 + hh * 4];
          oacc[dh2] = mfma_32x32x8(av, pk[g], oacc[dh2]);
        }
      }
    }
    __syncthreads();
  }

  lsum += __shfl_xor(lsum, 32);

  float* epiF = (float*)smem;                       // [2 wq][2048]
  float* lbuf = (float*)(smem + 16384);             // [4][32]
  unsigned short* Oq = (unsigned short*)(smem + 17408);  // [2 wq][32 q][68]

  if (l31 == lane) lbuf[wave * 32 + l31] = lsum;
  if (wk == 1) {
#pragma unroll
    for (int dh2 = 0; dh2 < 2; ++dh2)
#pragma unroll
      for (int r = 0; r < 16; ++r) {
        const int d = dh2 * 32 + (r & 3) + 8 * (r >> 2) + 4 * hh;
        epiF[wq * 2048 + d * 32 + l31] = oacc[dh2][r];
      }
  }
  __syncthreads();

  if (wk == 0) {
    const float linv = 1.0f / (lsum + lbuf[(wq * 2 + 1) * 32 + l31]);
#pragma unroll
    for (int dh2 = 0; dh2 < 2; ++dh2) {
#pragma unroll
      for (int r = 0; r < 16; r += 2) {
        const int d = dh2 * 32 + (r & 3) + 8 * (r >> 2) + 4 * hh;
        const float v0 = (oacc[dh2][r]     + epiF[wq * 2048 + d * 32 + l31]) * linv;
        const float v1 = (oacc[dh2][r + 1] + epiF[wq * 2048 + (d + 1) * 32 + l31]) * linv;
        *(unsigned*)&Oq[wq * 2176 + l31 * 68 + d] = pkbf(v0, v1);
      }
    }
  }
  __syncthreads();

  {
    const int qloc = tid >> 2, d0 = (tid & 3) * 16;
    const int base = (qloc >> 5) * 2176 + (qloc & 31) * 68 + d0;
    unsigned u[8];
#pragma unroll
    for (int i = 0; i < 8; ++i) u[i] = *(const unsigned*)&Oq[base + i * 2];
    unsigned short* dst = AO + ((size_t)(b * SEQ + qt * 64 + qloc)) * D_MODEL + h * 64 + d0;
    *(uint4*)dst       = make_uint4(u[0], u[1], u[2], u[3]);
    *(uint4*)(dst + 8) = make_uint4(u[4], u[5], u[6], u[7]);
  }
}

extern "C" void kernel_launch(void* const* d_in, const int* in_sizes, int n_in,
                              void* d_out, int out_size, void* d_ws, size_t ws_size,
                              hipStream_t stream) {
  const float* q  = (const float*)d_in[0];
  const float* k  = (const float*)d_in[1];
  const float* v  = (const float*)d_in[2];
  const float* Wq = (const float*)d_in[3];
  const float* bq = (const float*)d_in[4];
  const float* Wk = (const float*)d_in[5];
  const float* bk = (const float*)d_in[6];
  const float* Wv = (const float*)d_in[7];
  const float* bv = (const float*)d_in[8];
  const float* Wo = (const float*)d_in[9];
  const float* bo = (const float*)d_in[10];
  float* out = (float*)d_out;

  char* ws = (char*)d_ws;
  const size_t MB = 1ull << 20;
  unsigned short* Wqb = (unsigned short*)(ws + 24 * MB);
  unsigned short* Wkb = (unsigned short*)(ws + 26 * MB);
  unsigned short* Wvb = (unsigned short*)(ws + 28 * MB);
  unsigned short* Wob = (unsigned short*)(ws + 30 * MB);
  unsigned short* Qh  = (unsigned short*)(ws + 32 * MB);
  unsigned short* Kh  = (unsigned short*)(ws + 40 * MB);
  unsigned short* Vt  = (unsigned short*)(ws + 48 * MB);
  unsigned short* AO  = (unsigned short*)(ws + 56 * MB);

  castW<<<4096, 256, 0, stream>>>(Wq, Wk, Wv, Wo, Wqb, Wkb, Wvb, Wob);

  const float qscale = 0.125f * 1.44269504088896f;  // fold 1/sqrt(Dh) and log2(e) into Q
  qkv_gemm<<<768, 256, 0, stream>>>(q, k, v, Wqb, Wkb, Wvb, bq, bk, bv,
                                    Qh, Kh, Vt, qscale);

  attn<<<1024, 256, 0, stream>>>(Qh, Kh, Vt, AO);

  out_gemm<<<512, 256, 0, stream>>>(AO, Wob, bo, out);
}

// Round 6
// 257.195 us; speedup vs baseline: 1.0886x; 1.0886x over previous
//
#include <hip/hip_runtime.h>
#include <cstdint>
#include <cstddef>

#define DEVI __device__ __forceinline__

typedef short bf16x8 __attribute__((ext_vector_type(8)));
typedef short bf16x4 __attribute__((ext_vector_type(4)));
typedef float f32x4 __attribute__((ext_vector_type(4)));
typedef float f32x16 __attribute__((ext_vector_type(16)));
typedef unsigned short u16x4 __attribute__((ext_vector_type(4)));

constexpr int D_MODEL = 1024;
constexpr int HEADS = 16;
constexpr int DH = 64;
constexpr int SEQ = 2048;
constexpr int KDIM = 1024;

DEVI unsigned short f2bf(float f) {
  union { float f; unsigned u; } v; v.f = f;
  unsigned r = v.u + 0x7fffu + ((v.u >> 16) & 1u);
  return (unsigned short)(r >> 16);
}

// pack two fp32 -> two TRUNCATED bf16 in one dword (a = low16, b = high16)
DEVI unsigned pkbf(float a, float b) {
  return __builtin_amdgcn_perm(__float_as_uint(b), __float_as_uint(a), 0x07060302u);
}

DEVI void cp16(const void* g, void* l) {
  __builtin_amdgcn_global_load_lds(
      (const __attribute__((address_space(1))) void*)g,
      (__attribute__((address_space(3))) void*)l, 16, 0, 0);
}

DEVI f32x16 mfma_32x32x8(bf16x4 a, bf16x4 b, f32x16 c) {
#if __has_builtin(__builtin_amdgcn_mfma_f32_32x32x8bf16_1k)
  return __builtin_amdgcn_mfma_f32_32x32x8bf16_1k(a, b, c, 0, 0, 0);
#else
  asm volatile("v_mfma_f32_32x32x8_bf16 %0, %1, %2, %0" : "+v"(c) : "v"(a), "v"(b));
  return c;
#endif
}

#define BAR()        asm volatile("s_barrier" ::: "memory")
#define WAITVM(n)    asm volatile("s_waitcnt vmcnt(" #n ")" ::: "memory")

// ---------------- fused fp32 -> bf16 cast for all 7 tensors ----------------
__global__ void __launch_bounds__(256) castall(
    const float* __restrict__ q, const float* __restrict__ k, const float* __restrict__ v,
    const float* __restrict__ Wq, const float* __restrict__ Wk,
    const float* __restrict__ Wv, const float* __restrict__ Wo,
    unsigned short* __restrict__ qb, unsigned short* __restrict__ kb, unsigned short* __restrict__ vb,
    unsigned short* __restrict__ Wqb, unsigned short* __restrict__ Wkb,
    unsigned short* __restrict__ Wvb, unsigned short* __restrict__ Wob) {
  int bid = blockIdx.x;
  const float* s; unsigned short* d; int off;
  if (bid < 12288) {
    int w = bid >> 12; off = bid & 4095;
    s = (w == 0) ? q : ((w == 1) ? k : v);
    d = (w == 0) ? qb : ((w == 1) ? kb : vb);
  } else {
    int w = (bid - 12288) >> 10; off = bid & 1023;
    s = (w == 0) ? Wq : ((w == 1) ? Wk : ((w == 2) ? Wv : Wo));
    d = (w == 0) ? Wqb : ((w == 1) ? Wkb : ((w == 2) ? Wvb : Wob));
  }
  int i = (off * 256 + threadIdx.x) * 4;
  float4 x = *(const float4*)(s + i);
  u16x4 o; o[0] = f2bf(x.x); o[1] = f2bf(x.y); o[2] = f2bf(x.z); o[3] = f2bf(x.w);
  *(u16x4*)(d + i) = o;
}

// ---------------- QKV projection: 128x128 tile, double-buffered pipeline ----------
// C = A[M,K](bf16) * W[N,K]^T(bf16) + bias. mode 0 -> [B,H,S,Dh]; mode 1 -> [B,H,Dh,S].
// Pipeline: iter k issues stage k+1 into buf[(k+1)&1], waits vmcnt(4) (stage k's
// 4 older loads done, 4 newer stay in flight), raw s_barrier, computes buf[k&1].
__global__ void __launch_bounds__(256) qkv_gemm(
    const unsigned short* __restrict__ qb, const unsigned short* __restrict__ kb,
    const unsigned short* __restrict__ vb,
    const unsigned short* __restrict__ Wqb, const unsigned short* __restrict__ Wkb,
    const unsigned short* __restrict__ Wvb,
    const float* __restrict__ bq, const float* __restrict__ bk, const float* __restrict__ bv,
    unsigned short* __restrict__ Qh, unsigned short* __restrict__ Kh,
    unsigned short* __restrict__ Vt, float qscale) {
  __shared__ unsigned short As[2][128 * 32];
  __shared__ unsigned short Bs[2][128 * 32];
  const int bid = blockIdx.x, seg = bid >> 8, inner = bid & 255;
  const int bm = inner >> 3, bn = inner & 7;
  const unsigned short* A = (seg == 0) ? qb : ((seg == 1) ? kb : vb);
  const unsigned short* W = (seg == 0) ? Wqb : ((seg == 1) ? Wkb : Wvb);
  const float* bias = (seg == 0) ? bq : ((seg == 1) ? bk : bv);
  unsigned short* O = (seg == 0) ? Qh : ((seg == 1) ? Kh : Vt);
  const float oscale = (seg == 0) ? qscale : 1.0f;
  const int mode = (seg == 2) ? 1 : 0;

  const int tid = threadIdx.x, lane = tid & 63, wave = tid >> 6;
  const int l16 = lane & 15, quad = lane >> 4;
  const int wm = (wave >> 1) * 64, wn = (wave & 1) * 64;
  const int sw = (l16 >> 1) & 3;
  f32x4 acc[4][4] = {};

  // staging addresses: thread handles slots {tid, 256+tid}
  const int r0 = tid >> 2, p0 = tid & 3;
  const int c0 = (p0 ^ ((r0 >> 1) & 3)) * 8;
  const int r1 = (256 + tid) >> 2, p1 = tid & 3;
  const int c1 = (p1 ^ ((r1 >> 1) & 3)) * 8;
  const unsigned short* Arow0 = A + (size_t)(bm * 128 + r0) * KDIM + c0;
  const unsigned short* Arow1 = A + (size_t)(bm * 128 + r1) * KDIM + c1;
  const unsigned short* Wrow0 = W + (size_t)(bn * 128 + r0) * KDIM + c0;
  const unsigned short* Wrow1 = W + (size_t)(bn * 128 + r1) * KDIM + c1;

#define QKV_ISSUE(K0, P)                                    \
  do {                                                      \
    cp16(Arow0 + (K0), &As[P][tid * 8]);                    \
    cp16(Arow1 + (K0), &As[P][(256 + tid) * 8]);            \
    cp16(Wrow0 + (K0), &Bs[P][tid * 8]);                    \
    cp16(Wrow1 + (K0), &Bs[P][(256 + tid) * 8]);            \
  } while (0)

#define QKV_COMPUTE(P)                                                             \
  do {                                                                             \
    bf16x8 af[4], bfr[4];                                                          \
    _Pragma("unroll") for (int t = 0; t < 4; ++t)                                  \
        af[t] = *(const bf16x8*)&As[P][(wm + t * 16 + l16) * 32 + ((quad ^ sw) * 8)]; \
    _Pragma("unroll") for (int t = 0; t < 4; ++t)                                  \
        bfr[t] = *(const bf16x8*)&Bs[P][(wn + t * 16 + l16) * 32 + ((quad ^ sw) * 8)]; \
    _Pragma("unroll") for (int i = 0; i < 4; ++i)                                  \
        _Pragma("unroll") for (int j = 0; j < 4; ++j)                              \
            acc[i][j] = __builtin_amdgcn_mfma_f32_16x16x32_bf16(af[i], bfr[j],     \
                                                                acc[i][j], 0, 0, 0); \
  } while (0)

  QKV_ISSUE(0, 0);                      // prologue: stage 0 -> buf0
  for (int k = 0; k < 31; ++k) {
    BAR();                              // close compute k-1 (protects buf being loaded)
    QKV_ISSUE((k + 1) * 32, (k + 1) & 1);
    WAITVM(4);                          // stage k's 4 loads done; 4 newer in flight
    BAR();                              // stage k visible to all waves
    if (k & 1) QKV_COMPUTE(1); else QKV_COMPUTE(0);
  }
  WAITVM(0);
  BAR();
  QKV_COMPUTE(1);                       // stage 31 -> buf1

#pragma unroll
  for (int i = 0; i < 4; ++i) {
#pragma unroll
    for (int j = 0; j < 4; ++j) {
      const int col = bn * 128 + wn + j * 16 + l16;
      const float bv = bias[col];
#pragma unroll
      for (int r = 0; r < 4; ++r) {
        const int row = bm * 128 + wm + i * 16 + quad * 4 + r;
        const float val = (acc[i][j][r] + bv) * oscale;
        const int b = row >> 11, s = row & (SEQ - 1);
        const int h = col >> 6, d = col & (DH - 1);
        size_t idx;
        if (mode == 0) idx = ((size_t)(b * HEADS + h) * SEQ + s) * DH + d;
        else           idx = ((size_t)(b * HEADS + h) * DH + d) * SEQ + s;
        O[idx] = f2bf(val);
      }
    }
  }
#undef QKV_ISSUE
#undef QKV_COMPUTE
}

// ---------------- output projection: 64x128 tile, double-buffered pipeline --------
__global__ void __launch_bounds__(256) out_gemm(const unsigned short* __restrict__ AO,
                                                const unsigned short* __restrict__ Wob,
                                                const float* __restrict__ bo,
                                                float* __restrict__ out) {
  __shared__ unsigned short As[2][64 * 32];
  __shared__ unsigned short Bs[2][128 * 32];
  const int bid = blockIdx.x, bm = bid >> 3, bn = bid & 7;
  const int tid = threadIdx.x, lane = tid & 63, wave = tid >> 6;
  const int l16 = lane & 15, quad = lane >> 4;
  const int wn = wave * 32;
  const int sw = (l16 >> 1) & 3;
  f32x4 acc[4][2] = {};

  const int ra = tid >> 2, pa = tid & 3;
  const int ca = (pa ^ ((ra >> 1) & 3)) * 8;
  const int r1 = (256 + tid) >> 2;
  const int c1 = (pa ^ ((r1 >> 1) & 3)) * 8;
  const unsigned short* Arow  = AO + (size_t)(bm * 64 + ra) * KDIM + ca;
  const unsigned short* Wrow0 = Wob + (size_t)(bn * 128 + ra) * KDIM + ca;
  const unsigned short* Wrow1 = Wob + (size_t)(bn * 128 + r1) * KDIM + c1;

#define OUT_ISSUE(K0, P)                                    \
  do {                                                      \
    cp16(Arow + (K0), &As[P][tid * 8]);                     \
    cp16(Wrow0 + (K0), &Bs[P][tid * 8]);                    \
    cp16(Wrow1 + (K0), &Bs[P][(256 + tid) * 8]);            \
  } while (0)

#define OUT_COMPUTE(P)                                                             \
  do {                                                                             \
    bf16x8 af[4], bfr[2];                                                          \
    _Pragma("unroll") for (int t = 0; t < 4; ++t)                                  \
        af[t] = *(const bf16x8*)&As[P][(t * 16 + l16) * 32 + ((quad ^ sw) * 8)];   \
    _Pragma("unroll") for (int u = 0; u < 2; ++u)                                  \
        bfr[u] = *(const bf16x8*)&Bs[P][(wn + u * 16 + l16) * 32 + ((quad ^ sw) * 8)]; \
    _Pragma("unroll") for (int i = 0; i < 4; ++i)                                  \
        _Pragma("unroll") for (int j = 0; j < 2; ++j)                              \
            acc[i][j] = __builtin_amdgcn_mfma_f32_16x16x32_bf16(af[i], bfr[j],     \
                                                                acc[i][j], 0, 0, 0); \
  } while (0)

  OUT_ISSUE(0, 0);
  for (int k = 0; k < 31; ++k) {
    BAR();
    OUT_ISSUE((k + 1) * 32, (k + 1) & 1);
    WAITVM(3);
    BAR();
    if (k & 1) OUT_COMPUTE(1); else OUT_COMPUTE(0);
  }
  WAITVM(0);
  BAR();
  OUT_COMPUTE(1);

#pragma unroll
  for (int i = 0; i < 4; ++i)
#pragma unroll
    for (int j = 0; j < 2; ++j) {
      const int col = bn * 128 + wn + j * 16 + l16;
      const float bv = bo[col];
#pragma unroll
      for (int r = 0; r < 4; ++r) {
        const int row = bm * 64 + i * 16 + quad * 4 + r;
        out[(size_t)row * D_MODEL + col] = acc[i][j][r] + bv;
      }
    }
#undef OUT_ISSUE
#undef OUT_COMPUTE
}

// ---------------- flash attention, 32x32 register-resident P (unchanged) ----------
__global__ void __launch_bounds__(256) attn(const unsigned short* __restrict__ Qh,
                                            const unsigned short* __restrict__ Kh,
                                            const unsigned short* __restrict__ Vt,
                                            unsigned short* __restrict__ AO) {
  __shared__ __align__(16) char smem[32768];
  unsigned short* Ks = (unsigned short*)smem;            // [128 key][64 dh]
  unsigned short* Vs = (unsigned short*)(smem + 16384);  // [64 d][128 key]

  const int bid = blockIdx.x;
  const int qt = bid >> 5, head = bid & 31, b = head >> 4, h = head & 15;
  const int tid = threadIdx.x;
  const int lane = tid & 63, wave = tid >> 6;
  const int wq = wave >> 1, wk = wave & 1;
  const int l31 = lane & 31, hh = lane >> 5;

  const unsigned short* Qhead = Qh + (size_t)(b * HEADS + h) * SEQ * DH;
  const unsigned short* Khead = Kh + (size_t)(b * HEADS + h) * SEQ * DH;
  const unsigned short* Vhead = Vt + (size_t)(b * HEADS + h) * DH * SEQ;

  const int qrow = qt * 64 + wq * 32 + l31;
  bf16x8 aq[4];
#pragma unroll
  for (int it = 0; it < 4; ++it)
    aq[it] = *(const bf16x8*)&Qhead[(size_t)qrow * DH + it * 16 + hh * 8];

  f32x16 oacc[2] = {};
  float lsum = 0.f;

  for (int kc = 0; kc < SEQ / 128; ++kc) {
#pragma unroll
    for (int c = 0; c < 4; ++c) {
      int s = c * 256 + tid;
      int row = s >> 3, pblk = s & 7;
      int jb = pblk ^ (row & 7);
      cp16(Khead + (size_t)(kc * 128 + row) * DH + jb * 8, &Ks[s * 8]);
    }
#pragma unroll
    for (int c = 0; c < 4; ++c) {
      int s = c * 256 + tid;
      int d = s >> 4, pblk = s & 15;
      int jb = pblk ^ (d & 7);
      cp16(Vhead + (size_t)d * SEQ + kc * 128 + jb * 8, &Vs[s * 8]);
    }
    asm volatile("s_waitcnt vmcnt(0)" ::: "memory");
    __syncthreads();

#pragma unroll
    for (int sub = 0; sub < 2; ++sub) {
      const int kb32 = sub * 64 + wk * 32;
      const int key = kb32 + l31;

      f32x16 sa = {};
#pragma unroll
      for (int it = 0; it < 4; ++it) {
        const int sblk = (2 * it + hh) ^ (key & 7);
        bf16x8 ak = *(const bf16x8*)&Ks[key * 64 + sblk * 8];
        sa = __builtin_amdgcn_mfma_f32_32x32x16_bf16(ak, aq[it], sa, 0, 0, 0);
      }

      float p[16];
#pragma unroll
      for (int r = 0; r < 16; ++r) {
        p[r] = __builtin_amdgcn_exp2f(sa[r]);
        lsum += p[r];
      }
      bf16x4 pk[4];
#pragma unroll
      for (int g = 0; g < 4; ++g) {
        union { unsigned u[2]; bf16x4 s; } c;
        c.u[0] = pkbf(p[4 * g + 0], p[4 * g + 1]);
        c.u[1] = pkbf(p[4 * g + 2], p[4 * g + 3]);
        pk[g] = c.s;
      }

#pragma unroll
      for (int g = 0; g < 4; ++g) {
        const int gblk = sub * 8 + wk * 4 + g;
#pragma unroll
        for (int dh2 = 0; dh2 < 2; ++dh2) {
          const int d = dh2 * 32 + l31;
          const int sv = gblk ^ (d & 7);
          bf16x4 av = *(const bf16x4*)&Vs[d * 128 + sv * 8 + hh * 4];
          oacc[dh2] = mfma_32x32x8(av, pk[g], oacc[dh2]);
        }
      }
    }
    __syncthreads();
  }

  lsum += __shfl_xor(lsum, 32);

  float* epiF = (float*)smem;                       // [2 wq][2048]
  float* lbuf = (float*)(smem + 16384);             // [4][32]
  unsigned short* Oq = (unsigned short*)(smem + 17408);  // [2 wq][32 q][68]

  if (l31 == lane) lbuf[wave * 32 + l31] = lsum;
  if (wk == 1) {
#pragma unroll
    for (int dh2 = 0; dh2 < 2; ++dh2)
#pragma unroll
      for (int r = 0; r < 16; ++r) {
        const int d = dh2 * 32 + (r & 3) + 8 * (r >> 2) + 4 * hh;
        epiF[wq * 2048 + d * 32 + l31] = oacc[dh2][r];
      }
  }
  __syncthreads();

  if (wk == 0) {
    const float linv = 1.0f / (lsum + lbuf[(wq * 2 + 1) * 32 + l31]);
#pragma unroll
    for (int dh2 = 0; dh2 < 2; ++dh2) {
#pragma unroll
      for (int r = 0; r < 16; r += 2) {
        const int d = dh2 * 32 + (r & 3) + 8 * (r >> 2) + 4 * hh;
        const float v0 = (oacc[dh2][r]     + epiF[wq * 2048 + d * 32 + l31]) * linv;
        const float v1 = (oacc[dh2][r + 1] + epiF[wq * 2048 + (d + 1) * 32 + l31]) * linv;
        *(unsigned*)&Oq[wq * 2176 + l31 * 68 + d] = pkbf(v0, v1);
      }
    }
  }
  __syncthreads();

  {
    const int qloc = tid >> 2, d0 = (tid & 3) * 16;
    const int base = (qloc >> 5) * 2176 + (qloc & 31) * 68 + d0;
    unsigned u[8];
#pragma unroll
    for (int i = 0; i < 8; ++i) u[i] = *(const unsigned*)&Oq[base + i * 2];
    unsigned short* dst = AO + ((size_t)(b * SEQ + qt * 64 + qloc)) * D_MODEL + h * 64 + d0;
    *(uint4*)dst       = make_uint4(u[0], u[1], u[2], u[3]);
    *(uint4*)(dst + 8) = make_uint4(u[4], u[5], u[6], u[7]);
  }
}

extern "C" void kernel_launch(void* const* d_in, const int* in_sizes, int n_in,
                              void* d_out, int out_size, void* d_ws, size_t ws_size,
                              hipStream_t stream) {
  const float* q  = (const float*)d_in[0];
  const float* k  = (const float*)d_in[1];
  const float* v  = (const float*)d_in[2];
  const float* Wq = (const float*)d_in[3];
  const float* bq = (const float*)d_in[4];
  const float* Wk = (const float*)d_in[5];
  const float* bk = (const float*)d_in[6];
  const float* Wv = (const float*)d_in[7];
  const float* bv = (const float*)d_in[8];
  const float* Wo = (const float*)d_in[9];
  const float* bo = (const float*)d_in[10];
  float* out = (float*)d_out;

  char* ws = (char*)d_ws;
  const size_t MB = 1ull << 20;
  unsigned short* qb  = (unsigned short*)(ws + 0 * MB);
  unsigned short* kb  = (unsigned short*)(ws + 8 * MB);
  unsigned short* vb  = (unsigned short*)(ws + 16 * MB);
  unsigned short* Wqb = (unsigned short*)(ws + 24 * MB);
  unsigned short* Wkb = (unsigned short*)(ws + 26 * MB);
  unsigned short* Wvb = (unsigned short*)(ws + 28 * MB);
  unsigned short* Wob = (unsigned short*)(ws + 30 * MB);
  unsigned short* Qh  = (unsigned short*)(ws + 32 * MB);
  unsigned short* Kh  = (unsigned short*)(ws + 40 * MB);
  unsigned short* Vt  = (unsigned short*)(ws + 48 * MB);
  unsigned short* AO  = (unsigned short*)(ws + 56 * MB);

  castall<<<16384, 256, 0, stream>>>(q, k, v, Wq, Wk, Wv, Wo,
                                     qb, kb, vb, Wqb, Wkb, Wvb, Wob);

  const float qscale = 0.125f * 1.44269504088896f;  // fold 1/sqrt(Dh) and log2(e) into Q
  qkv_gemm<<<768, 256, 0, stream>>>(qb, kb, vb, Wqb, Wkb, Wvb, bq, bk, bv,
                                    Qh, Kh, Vt, qscale);

  attn<<<1024, 256, 0, stream>>>(Qh, Kh, Vt, AO);

  out_gemm<<<512, 256, 0, stream>>>(AO, Wob, bo, out);
}

// Round 7
// 233.294 us; speedup vs baseline: 1.2001x; 1.1025x over previous
//
#include <hip/hip_runtime.h>
#include <cstdint>
#include <cstddef>

#define DEVI __device__ __forceinline__

typedef short bf16x8 __attribute__((ext_vector_type(8)));
typedef short bf16x4 __attribute__((ext_vector_type(4)));
typedef float f32x4 __attribute__((ext_vector_type(4)));
typedef float f32x16 __attribute__((ext_vector_type(16)));
typedef unsigned short u16x4 __attribute__((ext_vector_type(4)));

constexpr int D_MODEL = 1024;
constexpr int HEADS = 16;
constexpr int DH = 64;
constexpr int SEQ = 2048;
constexpr int KDIM = 1024;

DEVI unsigned short f2bf(float f) {
  union { float f; unsigned u; } v; v.f = f;
  unsigned r = v.u + 0x7fffu + ((v.u >> 16) & 1u);
  return (unsigned short)(r >> 16);
}

// pack two fp32 -> two TRUNCATED bf16 in one dword (a = low16, b = high16)
DEVI unsigned pkbf(float a, float b) {
  return __builtin_amdgcn_perm(__float_as_uint(b), __float_as_uint(a), 0x07060302u);
}

DEVI void cp16(const void* g, void* l) {
  __builtin_amdgcn_global_load_lds(
      (const __attribute__((address_space(1))) void*)g,
      (__attribute__((address_space(3))) void*)l, 16, 0, 0);
}

DEVI f32x16 mfma_32x32x8(bf16x4 a, bf16x4 b, f32x16 c) {
#if __has_builtin(__builtin_amdgcn_mfma_f32_32x32x8bf16_1k)
  return __builtin_amdgcn_mfma_f32_32x32x8bf16_1k(a, b, c, 0, 0, 0);
#else
  asm volatile("v_mfma_f32_32x32x8_bf16 %0, %1, %2, %0" : "+v"(c) : "v"(a), "v"(b));
  return c;
#endif
}

#define BAR()        asm volatile("s_barrier" ::: "memory")
#define WAITVM(n)    asm volatile("s_waitcnt vmcnt(" #n ")" ::: "memory")

// ---------------- fused fp32 -> bf16 cast for all 7 tensors ----------------
__global__ void __launch_bounds__(256) castall(
    const float* __restrict__ q, const float* __restrict__ k, const float* __restrict__ v,
    const float* __restrict__ Wq, const float* __restrict__ Wk,
    const float* __restrict__ Wv, const float* __restrict__ Wo,
    unsigned short* __restrict__ qb, unsigned short* __restrict__ kb, unsigned short* __restrict__ vb,
    unsigned short* __restrict__ Wqb, unsigned short* __restrict__ Wkb,
    unsigned short* __restrict__ Wvb, unsigned short* __restrict__ Wob) {
  int bid = blockIdx.x;
  const float* s; unsigned short* d; int off;
  if (bid < 12288) {
    int w = bid >> 12; off = bid & 4095;
    s = (w == 0) ? q : ((w == 1) ? k : v);
    d = (w == 0) ? qb : ((w == 1) ? kb : vb);
  } else {
    int w = (bid - 12288) >> 10; off = bid & 1023;
    s = (w == 0) ? Wq : ((w == 1) ? Wk : ((w == 2) ? Wv : Wo));
    d = (w == 0) ? Wqb : ((w == 1) ? Wkb : ((w == 2) ? Wvb : Wob));
  }
  int i = (off * 256 + threadIdx.x) * 4;
  float4 x = *(const float4*)(s + i);
  u16x4 o; o[0] = f2bf(x.x); o[1] = f2bf(x.y); o[2] = f2bf(x.z); o[3] = f2bf(x.w);
  *(u16x4*)(d + i) = o;
}

// ---------------- QKV projection: 128x128 tile, triple-buffered, XCD-local ----------
// inner = bn*32 + bm: the 8 blocks sharing an A-tile (same bm) have bids that are
// congruent mod 8 -> same XCD. Per-XCD working set per segment = A 1MB + W 2MB < 4MB L2.
// Pipeline: 2-stage lead (issue k+2, wait vmcnt(8) for stage k), raw s_barrier.
__global__ void __launch_bounds__(256) qkv_gemm(
    const unsigned short* __restrict__ qb, const unsigned short* __restrict__ kb,
    const unsigned short* __restrict__ vb,
    const unsigned short* __restrict__ Wqb, const unsigned short* __restrict__ Wkb,
    const unsigned short* __restrict__ Wvb,
    const float* __restrict__ bq, const float* __restrict__ bk, const float* __restrict__ bv,
    unsigned short* __restrict__ Qh, unsigned short* __restrict__ Kh,
    unsigned short* __restrict__ Vt, float qscale) {
  __shared__ unsigned short As[3][128 * 32];
  __shared__ unsigned short Bs[3][128 * 32];
  const int bid = blockIdx.x, seg = bid >> 8, inner = bid & 255;
  const int bm = inner & 31, bn = inner >> 5;          // XCD-local swizzle
  const unsigned short* A = (seg == 0) ? qb : ((seg == 1) ? kb : vb);
  const unsigned short* W = (seg == 0) ? Wqb : ((seg == 1) ? Wkb : Wvb);
  const float* bias = (seg == 0) ? bq : ((seg == 1) ? bk : bv);
  unsigned short* O = (seg == 0) ? Qh : ((seg == 1) ? Kh : Vt);
  const float oscale = (seg == 0) ? qscale : 1.0f;
  const int mode = (seg == 2) ? 1 : 0;

  const int tid = threadIdx.x, lane = tid & 63, wave = tid >> 6;
  const int l16 = lane & 15, quad = lane >> 4;
  const int wm = (wave >> 1) * 64, wn = (wave & 1) * 64;
  const int sw = (l16 >> 1) & 3;
  f32x4 acc[4][4] = {};

  const int r0 = tid >> 2, p0 = tid & 3;
  const int c0 = (p0 ^ ((r0 >> 1) & 3)) * 8;
  const int r1 = (256 + tid) >> 2;
  const int c1 = (p0 ^ ((r1 >> 1) & 3)) * 8;
  const unsigned short* Arow0 = A + (size_t)(bm * 128 + r0) * KDIM + c0;
  const unsigned short* Arow1 = A + (size_t)(bm * 128 + r1) * KDIM + c1;
  const unsigned short* Wrow0 = W + (size_t)(bn * 128 + r0) * KDIM + c0;
  const unsigned short* Wrow1 = W + (size_t)(bn * 128 + r1) * KDIM + c1;

#define QKV_ISSUE(K0, P)                                    \
  do {                                                      \
    cp16(Arow0 + (K0), &As[P][tid * 8]);                    \
    cp16(Arow1 + (K0), &As[P][(256 + tid) * 8]);            \
    cp16(Wrow0 + (K0), &Bs[P][tid * 8]);                    \
    cp16(Wrow1 + (K0), &Bs[P][(256 + tid) * 8]);            \
  } while (0)

#define QKV_COMPUTE(P)                                                             \
  do {                                                                             \
    bf16x8 af[4], bfr[4];                                                          \
    _Pragma("unroll") for (int t = 0; t < 4; ++t)                                  \
        af[t] = *(const bf16x8*)&As[P][(wm + t * 16 + l16) * 32 + ((quad ^ sw) * 8)]; \
    _Pragma("unroll") for (int t = 0; t < 4; ++t)                                  \
        bfr[t] = *(const bf16x8*)&Bs[P][(wn + t * 16 + l16) * 32 + ((quad ^ sw) * 8)]; \
    _Pragma("unroll") for (int i = 0; i < 4; ++i)                                  \
        _Pragma("unroll") for (int j = 0; j < 4; ++j)                              \
            acc[i][j] = __builtin_amdgcn_mfma_f32_16x16x32_bf16(af[i], bfr[j],     \
                                                                acc[i][j], 0, 0, 0); \
  } while (0)

  QKV_ISSUE(0, 0);
  QKV_ISSUE(32, 1);
  for (int k = 0; k < 30; k += 3) {
    BAR(); QKV_ISSUE((k + 2) * 32, 2); WAITVM(8); BAR(); QKV_COMPUTE(0);
    BAR(); QKV_ISSUE((k + 3) * 32, 0); WAITVM(8); BAR(); QKV_COMPUTE(1);
    BAR(); QKV_ISSUE((k + 4) * 32, 1); WAITVM(8); BAR(); QKV_COMPUTE(2);
  }
  WAITVM(4); BAR(); QKV_COMPUTE(0);   // stage 30
  WAITVM(0); BAR(); QKV_COMPUTE(1);   // stage 31

#pragma unroll
  for (int i = 0; i < 4; ++i) {
#pragma unroll
    for (int j = 0; j < 4; ++j) {
      const int col = bn * 128 + wn + j * 16 + l16;
      const float bv = bias[col];
#pragma unroll
      for (int r = 0; r < 4; ++r) {
        const int row = bm * 128 + wm + i * 16 + quad * 4 + r;
        const float val = (acc[i][j][r] + bv) * oscale;
        const int b = row >> 11, s = row & (SEQ - 1);
        const int h = col >> 6, d = col & (DH - 1);
        size_t idx;
        if (mode == 0) idx = ((size_t)(b * HEADS + h) * SEQ + s) * DH + d;
        else           idx = ((size_t)(b * HEADS + h) * DH + d) * SEQ + s;
        O[idx] = f2bf(val);
      }
    }
  }
#undef QKV_ISSUE
#undef QKV_COMPUTE
}

// ---------------- output projection: 64x128 tile, triple-buffered, XCD-local ------
// bm = bid&63: the 8 blocks sharing an A-tile are congruent mod 8 -> same XCD.
__global__ void __launch_bounds__(256) out_gemm(const unsigned short* __restrict__ AO,
                                                const unsigned short* __restrict__ Wob,
                                                const float* __restrict__ bo,
                                                float* __restrict__ out) {
  __shared__ unsigned short As[3][64 * 32];
  __shared__ unsigned short Bs[3][128 * 32];
  const int bid = blockIdx.x, bm = bid & 63, bn = bid >> 6;
  const int tid = threadIdx.x, lane = tid & 63, wave = tid >> 6;
  const int l16 = lane & 15, quad = lane >> 4;
  const int wn = wave * 32;
  const int sw = (l16 >> 1) & 3;
  f32x4 acc[4][2] = {};

  const int ra = tid >> 2, pa = tid & 3;
  const int ca = (pa ^ ((ra >> 1) & 3)) * 8;
  const int r1 = (256 + tid) >> 2;
  const int c1 = (pa ^ ((r1 >> 1) & 3)) * 8;
  const unsigned short* Arow  = AO + (size_t)(bm * 64 + ra) * KDIM + ca;
  const unsigned short* Wrow0 = Wob + (size_t)(bn * 128 + ra) * KDIM + ca;
  const unsigned short* Wrow1 = Wob + (size_t)(bn * 128 + r1) * KDIM + c1;

#define OUT_ISSUE(K0, P)                                    \
  do {                                                      \
    cp16(Arow + (K0), &As[P][tid * 8]);                     \
    cp16(Wrow0 + (K0), &Bs[P][tid * 8]);                    \
    cp16(Wrow1 + (K0), &Bs[P][(256 + tid) * 8]);            \
  } while (0)

#define OUT_COMPUTE(P)                                                             \
  do {                                                                             \
    bf16x8 af[4], bfr[2];                                                          \
    _Pragma("unroll") for (int t = 0; t < 4; ++t)                                  \
        af[t] = *(const bf16x8*)&As[P][(t * 16 + l16) * 32 + ((quad ^ sw) * 8)];   \
    _Pragma("unroll") for (int u = 0; u < 2; ++u)                                  \
        bfr[u] = *(const bf16x8*)&Bs[P][(wn + u * 16 + l16) * 32 + ((quad ^ sw) * 8)]; \
    _Pragma("unroll") for (int i = 0; i < 4; ++i)                                  \
        _Pragma("unroll") for (int j = 0; j < 2; ++j)                              \
            acc[i][j] = __builtin_amdgcn_mfma_f32_16x16x32_bf16(af[i], bfr[j],     \
                                                                acc[i][j], 0, 0, 0); \
  } while (0)

  OUT_ISSUE(0, 0);
  OUT_ISSUE(32, 1);
  for (int k = 0; k < 30; k += 3) {
    BAR(); OUT_ISSUE((k + 2) * 32, 2); WAITVM(6); BAR(); OUT_COMPUTE(0);
    BAR(); OUT_ISSUE((k + 3) * 32, 0); WAITVM(6); BAR(); OUT_COMPUTE(1);
    BAR(); OUT_ISSUE((k + 4) * 32, 1); WAITVM(6); BAR(); OUT_COMPUTE(2);
  }
  WAITVM(3); BAR(); OUT_COMPUTE(0);   // stage 30
  WAITVM(0); BAR(); OUT_COMPUTE(1);   // stage 31

#pragma unroll
  for (int i = 0; i < 4; ++i)
#pragma unroll
    for (int j = 0; j < 2; ++j) {
      const int col = bn * 128 + wn + j * 16 + l16;
      const float bv = bo[col];
#pragma unroll
      for (int r = 0; r < 4; ++r) {
        const int row = bm * 64 + i * 16 + quad * 4 + r;
        out[(size_t)row * D_MODEL + col] = acc[i][j][r] + bv;
      }
    }
#undef OUT_ISSUE
#undef OUT_COMPUTE
}

// ---------------- flash attention, 32x32 register-resident P (unchanged) ----------
__global__ void __launch_bounds__(256) attn(const unsigned short* __restrict__ Qh,
                                            const unsigned short* __restrict__ Kh,
                                            const unsigned short* __restrict__ Vt,
                                            unsigned short* __restrict__ AO) {
  __shared__ __align__(16) char smem[32768];
  unsigned short* Ks = (unsigned short*)smem;            // [128 key][64 dh]
  unsigned short* Vs = (unsigned short*)(smem + 16384);  // [64 d][128 key]

  const int bid = blockIdx.x;
  const int qt = bid >> 5, head = bid & 31, b = head >> 4, h = head & 15;
  const int tid = threadIdx.x;
  const int lane = tid & 63, wave = tid >> 6;
  const int wq = wave >> 1, wk = wave & 1;
  const int l31 = lane & 31, hh = lane >> 5;

  const unsigned short* Qhead = Qh + (size_t)(b * HEADS + h) * SEQ * DH;
  const unsigned short* Khead = Kh + (size_t)(b * HEADS + h) * SEQ * DH;
  const unsigned short* Vhead = Vt + (size_t)(b * HEADS + h) * DH * SEQ;

  const int qrow = qt * 64 + wq * 32 + l31;
  bf16x8 aq[4];
#pragma unroll
  for (int it = 0; it < 4; ++it)
    aq[it] = *(const bf16x8*)&Qhead[(size_t)qrow * DH + it * 16 + hh * 8];

  f32x16 oacc[2] = {};
  float lsum = 0.f;

  for (int kc = 0; kc < SEQ / 128; ++kc) {
#pragma unroll
    for (int c = 0; c < 4; ++c) {
      int s = c * 256 + tid;
      int row = s >> 3, pblk = s & 7;
      int jb = pblk ^ (row & 7);
      cp16(Khead + (size_t)(kc * 128 + row) * DH + jb * 8, &Ks[s * 8]);
    }
#pragma unroll
    for (int c = 0; c < 4; ++c) {
      int s = c * 256 + tid;
      int d = s >> 4, pblk = s & 15;
      int jb = pblk ^ (d & 7);
      cp16(Vhead + (size_t)d * SEQ + kc * 128 + jb * 8, &Vs[s * 8]);
    }
    asm volatile("s_waitcnt vmcnt(0)" ::: "memory");
    __syncthreads();

#pragma unroll
    for (int sub = 0; sub < 2; ++sub) {
      const int kb32 = sub * 64 + wk * 32;
      const int key = kb32 + l31;

      f32x16 sa = {};
#pragma unroll
      for (int it = 0; it < 4; ++it) {
        const int sblk = (2 * it + hh) ^ (key & 7);
        bf16x8 ak = *(const bf16x8*)&Ks[key * 64 + sblk * 8];
        sa = __builtin_amdgcn_mfma_f32_32x32x16_bf16(ak, aq[it], sa, 0, 0, 0);
      }

      float p[16];
#pragma unroll
      for (int r = 0; r < 16; ++r) {
        p[r] = __builtin_amdgcn_exp2f(sa[r]);
        lsum += p[r];
      }
      bf16x4 pk[4];
#pragma unroll
      for (int g = 0; g < 4; ++g) {
        union { unsigned u[2]; bf16x4 s; } c;
        c.u[0] = pkbf(p[4 * g + 0], p[4 * g + 1]);
        c.u[1] = pkbf(p[4 * g + 2], p[4 * g + 3]);
        pk[g] = c.s;
      }

#pragma unroll
      for (int g = 0; g < 4; ++g) {
        const int gblk = sub * 8 + wk * 4 + g;
#pragma unroll
        for (int dh2 = 0; dh2 < 2; ++dh2) {
          const int d = dh2 * 32 + l31;
          const int sv = gblk ^ (d & 7);
          bf16x4 av = *(const bf16x4*)&Vs[d * 128 + sv * 8 + hh * 4];
          oacc[dh2] = mfma_32x32x8(av, pk[g], oacc[dh2]);
        }
      }
    }
    __syncthreads();
  }

  lsum += __shfl_xor(lsum, 32);

  float* epiF = (float*)smem;                       // [2 wq][2048]
  float* lbuf = (float*)(smem + 16384);             // [4][32]
  unsigned short* Oq = (unsigned short*)(smem + 17408);  // [2 wq][32 q][68]

  if (l31 == lane) lbuf[wave * 32 + l31] = lsum;
  if (wk == 1) {
#pragma unroll
    for (int dh2 = 0; dh2 < 2; ++dh2)
#pragma unroll
      for (int r = 0; r < 16; ++r) {
        const int d = dh2 * 32 + (r & 3) + 8 * (r >> 2) + 4 * hh;
        epiF[wq * 2048 + d * 32 + l31] = oacc[dh2][r];
      }
  }
  __syncthreads();

  if (wk == 0) {
    const float linv = 1.0f / (lsum + lbuf[(wq * 2 + 1) * 32 + l31]);
#pragma unroll
    for (int dh2 = 0; dh2 < 2; ++dh2) {
#pragma unroll
      for (int r = 0; r < 16; r += 2) {
        const int d = dh2 * 32 + (r & 3) + 8 * (r >> 2) + 4 * hh;
        const float v0 = (oacc[dh2][r]     + epiF[wq * 2048 + d * 32 + l31]) * linv;
        const float v1 = (oacc[dh2][r + 1] + epiF[wq * 2048 + (d + 1) * 32 + l31]) * linv;
        *(unsigned*)&Oq[wq * 2176 + l31 * 68 + d] = pkbf(v0, v1);
      }
    }
  }
  __syncthreads();

  {
    const int qloc = tid >> 2, d0 = (tid & 3) * 16;
    const int base = (qloc >> 5) * 2176 + (qloc & 31) * 68 + d0;
    unsigned u[8];
#pragma unroll
    for (int i = 0; i < 8; ++i) u[i] = *(const unsigned*)&Oq[base + i * 2];
    unsigned short* dst = AO + ((size_t)(b * SEQ + qt * 64 + qloc)) * D_MODEL + h * 64 + d0;
    *(uint4*)dst       = make_uint4(u[0], u[1], u[2], u[3]);
    *(uint4*)(dst + 8) = make_uint4(u[4], u[5], u[6], u[7]);
  }
}

extern "C" void kernel_launch(void* const* d_in, const int* in_sizes, int n_in,
                              void* d_out, int out_size, void* d_ws, size_t ws_size,
                              hipStream_t stream) {
  const float* q  = (const float*)d_in[0];
  const float* k  = (const float*)d_in[1];
  const float* v  = (const float*)d_in[2];
  const float* Wq = (const float*)d_in[3];
  const float* bq = (const float*)d_in[4];
  const float* Wk = (const float*)d_in[5];
  const float* bk = (const float*)d_in[6];
  const float* Wv = (const float*)d_in[7];
  const float* bv = (const float*)d_in[8];
  const float* Wo = (const float*)d_in[9];
  const float* bo = (const float*)d_in[10];
  float* out = (float*)d_out;

  char* ws = (char*)d_ws;
  const size_t MB = 1ull << 20;
  unsigned short* qb  = (unsigned short*)(ws + 0 * MB);
  unsigned short* kb  = (unsigned short*)(ws + 8 * MB);
  unsigned short* vb  = (unsigned short*)(ws + 16 * MB);
  unsigned short* Wqb = (unsigned short*)(ws + 24 * MB);
  unsigned short* Wkb = (unsigned short*)(ws + 26 * MB);
  unsigned short* Wvb = (unsigned short*)(ws + 28 * MB);
  unsigned short* Wob = (unsigned short*)(ws + 30 * MB);
  unsigned short* Qh  = (unsigned short*)(ws + 32 * MB);
  unsigned short* Kh  = (unsigned short*)(ws + 40 * MB);
  unsigned short* Vt  = (unsigned short*)(ws + 48 * MB);
  unsigned short* AO  = (unsigned short*)(ws + 56 * MB);

  castall<<<16384, 256, 0, stream>>>(q, k, v, Wq, Wk, Wv, Wo,
                                     qb, kb, vb, Wqb, Wkb, Wvb, Wob);

  const float qscale = 0.125f * 1.44269504088896f;  // fold 1/sqrt(Dh) and log2(e) into Q
  qkv_gemm<<<768, 256, 0, stream>>>(qb, kb, vb, Wqb, Wkb, Wvb, bq, bk, bv,
                                    Qh, Kh, Vt, qscale);

  attn<<<1024, 256, 0, stream>>>(Qh, Kh, Vt, AO);

  out_gemm<<<512, 256, 0, stream>>>(AO, Wob, bo, out);
}